// Round 1
// baseline (2705.365 us; speedup 1.0000x reference)
//
#include <hip/hip_runtime.h>
#include <cstddef>
#include <cstdint>

#define NSEQ 2048
#define NB 2
#define NH 16
#define WINDOW 512

// ---------------------------------------------------------------------------
// f32 GEMM: C[M,N] = A[M,K] @ B[K,N].  A row-major lda=K, B row-major ldb,
// C row-major ldc (C may be a column-slice of a wider buffer).
// 128x128 tile, BK=8, 256 threads, 8x8 per thread (interleaved 4+4 rows/cols).
// ---------------------------------------------------------------------------
__global__ __launch_bounds__(256)
void gemm_f32(const float* __restrict__ A, const float* __restrict__ B,
              float* __restrict__ C, int M, int N, int K, int ldb, int ldc)
{
    __shared__ float As[8][128];
    __shared__ float Bs[8][128];
    const int t  = threadIdx.x;
    const int tx = t & 15, ty = t >> 4;
    const int bm = blockIdx.y * 128;
    const int bn = blockIdx.x * 128;

    const int arow = t >> 1, ac4 = (t & 1) * 4;   // A tile: 128 rows x 8 k
    const int brow = t >> 5, bc4 = (t & 31) * 4;  // B tile: 8 k x 128 cols

    const float* Aptr = A + (size_t)(bm + arow) * K + ac4;
    const float* Bptr = B + (size_t)brow * ldb + bn + bc4;

    float acc[8][8];
#pragma unroll
    for (int i = 0; i < 8; ++i)
#pragma unroll
        for (int j = 0; j < 8; ++j) acc[i][j] = 0.f;

    float4 av = *(const float4*)Aptr;
    float4 bv = *(const float4*)Bptr;

    for (int k0 = 8;; k0 += 8) {
        __syncthreads();
        As[ac4 + 0][arow] = av.x; As[ac4 + 1][arow] = av.y;
        As[ac4 + 2][arow] = av.z; As[ac4 + 3][arow] = av.w;
        *(float4*)&Bs[brow][bc4] = bv;
        __syncthreads();
        if (k0 < K) {
            av = *(const float4*)(Aptr + k0);
            bv = *(const float4*)(Bptr + (size_t)k0 * ldb);
        }
#pragma unroll
        for (int k = 0; k < 8; ++k) {
            float4 a0 = *(const float4*)&As[k][ty * 4];
            float4 a1 = *(const float4*)&As[k][64 + ty * 4];
            float4 b0 = *(const float4*)&Bs[k][tx * 4];
            float4 b1 = *(const float4*)&Bs[k][64 + tx * 4];
            float ar[8] = {a0.x, a0.y, a0.z, a0.w, a1.x, a1.y, a1.z, a1.w};
            float br[8] = {b0.x, b0.y, b0.z, b0.w, b1.x, b1.y, b1.z, b1.w};
#pragma unroll
            for (int i = 0; i < 8; ++i)
#pragma unroll
                for (int j = 0; j < 8; ++j)
                    acc[i][j] += ar[i] * br[j];
        }
        if (k0 >= K) break;
    }

#pragma unroll
    for (int i = 0; i < 8; ++i) {
        int r = bm + ((i < 4) ? (ty * 4 + i) : (64 + ty * 4 + (i - 4)));
        float* Crow = C + (size_t)r * ldc + bn;
        *(float4*)&Crow[tx * 4]      = make_float4(acc[i][0], acc[i][1], acc[i][2], acc[i][3]);
        *(float4*)&Crow[64 + tx * 4] = make_float4(acc[i][4], acc[i][5], acc[i][6], acc[i][7]);
    }
}

// ---------------------------------------------------------------------------
// Flash-style attend with sink + "mask j>i && j-i<=WINDOW" band mask.
// Q rows scaled by 0.125 at load (DIM_HEAD**-0.5, fixed for both attends).
// Online softmax init: m = sink[h], l = 1  (sink column, later dropped).
// QT = 64 (DK=64) or 32 (DK=128) query rows per block; KT = 32 key rows.
// 256 threads: ty=t/16 owns rows {ty+16*mi}, tx=t%16 owns cols {tx, tx+16}
// and V slices {tx*4..+3, 64+tx*4..+3}.
// SILU: apply x*sigmoid(x) to the normalized output (attend1 -> hiddens).
// ---------------------------------------------------------------------------
template <int DK, int DV, bool SILU>
__global__ __launch_bounds__(256)
void attend(const float* __restrict__ Q, int ldq,
            const float* __restrict__ Kp, int ldk,
            const float* __restrict__ Vp, int ldv,
            const float* __restrict__ sink,
            float* __restrict__ Op, int ldo)
{
    constexpr int QT = (DK == 64) ? 64 : 32;
    constexpr int KT = 32;
    constexpr int MI = QT / 16;      // rows per thread
    constexpr int NO = DV / 16;      // output floats per row per thread
    constexpr int LDQ = DK + 4, LDK = DK + 4, LDV = DV + 4, LDP = KT + 4;

    __shared__ float Qs[QT][LDQ];
    __shared__ float Ks[KT][LDK];
    __shared__ float Vs[KT][LDV];
    __shared__ float Ps[QT][LDP];

    const int t = threadIdx.x, tx = t & 15, ty = t >> 4;
    const int bh = blockIdx.x, b = bh >> 4, h = bh & 15;
    const int i0 = blockIdx.y * QT;

    const float* qb = Q + (size_t)b * NSEQ * ldq + h * DK;
    const float* kb = Kp + (size_t)b * NSEQ * ldk + h * DK;
    const float* vb = Vp + (size_t)b * NSEQ * ldv + h * DV;

    for (int idx = t * 4; idx < QT * DK; idx += 1024) {
        int r = idx / DK, c = idx % DK;
        float4 v = *(const float4*)(qb + (size_t)(i0 + r) * ldq + c);
        v.x *= 0.125f; v.y *= 0.125f; v.z *= 0.125f; v.w *= 0.125f;
        *(float4*)&Qs[r][c] = v;
    }

    float m[MI], l[MI], o[MI][NO];
    const float sv = sink[h];
#pragma unroll
    for (int mi = 0; mi < MI; ++mi) {
        m[mi] = sv; l[mi] = 1.0f;
#pragma unroll
        for (int d = 0; d < NO; ++d) o[mi][d] = 0.f;
    }

    for (int j0 = 0; j0 < NSEQ; j0 += KT) {
        const int dd = j0 - i0;
        if (dd >= QT && dd + KT - 1 <= WINDOW) continue;  // tile fully masked

        __syncthreads();  // previous PV done reading Ks/Vs/Ps
        for (int idx = t * 4; idx < KT * DK; idx += 1024) {
            int r = idx / DK, c = idx % DK;
            *(float4*)&Ks[r][c] = *(const float4*)(kb + (size_t)(j0 + r) * ldk + c);
        }
        for (int idx = t * 4; idx < KT * DV; idx += 1024) {
            int r = idx / DV, c = idx % DV;
            *(float4*)&Vs[r][c] = *(const float4*)(vb + (size_t)(j0 + r) * ldv + c);
        }
        __syncthreads();  // K/V ready

        float s[MI][2];
#pragma unroll
        for (int mi = 0; mi < MI; ++mi) { s[mi][0] = 0.f; s[mi][1] = 0.f; }
#pragma unroll 8
        for (int k = 0; k < DK; ++k) {
            float b0 = Ks[tx][k], b1 = Ks[tx + 16][k];
#pragma unroll
            for (int mi = 0; mi < MI; ++mi) {
                float a = Qs[ty + 16 * mi][k];
                s[mi][0] += a * b0;
                s[mi][1] += a * b1;
            }
        }

#pragma unroll
        for (int mi = 0; mi < MI; ++mi) {
            const int i = i0 + ty + 16 * mi;
            const int ja = j0 + tx, jb2 = j0 + tx + 16;
            if (ja > i && (ja - i) <= WINDOW)  s[mi][0] = -3.0e38f;
            if (jb2 > i && (jb2 - i) <= WINDOW) s[mi][1] = -3.0e38f;
            float mx = fmaxf(s[mi][0], s[mi][1]);
#pragma unroll
            for (int off = 1; off < 16; off <<= 1)
                mx = fmaxf(mx, __shfl_xor(mx, off));
            const float nm = fmaxf(m[mi], mx);
            const float corr = __expf(m[mi] - nm);
            const float p0 = __expf(s[mi][0] - nm);
            const float p1 = __expf(s[mi][1] - nm);
            float rs = p0 + p1;
#pragma unroll
            for (int off = 1; off < 16; off <<= 1)
                rs += __shfl_xor(rs, off);
            l[mi] = l[mi] * corr + rs;
            m[mi] = nm;
#pragma unroll
            for (int d = 0; d < NO; ++d) o[mi][d] *= corr;
            Ps[ty + 16 * mi][tx]      = p0;
            Ps[ty + 16 * mi][tx + 16] = p1;
        }
        __syncthreads();  // P ready

#pragma unroll 4
        for (int j = 0; j < KT; ++j) {
            float4 v0 = *(const float4*)&Vs[j][tx * 4];
#pragma unroll
            for (int mi = 0; mi < MI; ++mi) {
                float p = Ps[ty + 16 * mi][j];
                o[mi][0] += p * v0.x; o[mi][1] += p * v0.y;
                o[mi][2] += p * v0.z; o[mi][3] += p * v0.w;
            }
            if constexpr (DV == 128) {
                float4 v1 = *(const float4*)&Vs[j][64 + tx * 4];
#pragma unroll
                for (int mi = 0; mi < MI; ++mi) {
                    float p = Ps[ty + 16 * mi][j];
                    o[mi][4] += p * v1.x; o[mi][5] += p * v1.y;
                    o[mi][6] += p * v1.z; o[mi][7] += p * v1.w;
                }
            }
        }
    }

    float* ob = Op + (size_t)b * NSEQ * ldo + h * DV;
#pragma unroll
    for (int mi = 0; mi < MI; ++mi) {
        const int i = i0 + ty + 16 * mi;
        const float inv = 1.0f / l[mi];
        float vals[NO];
#pragma unroll
        for (int d = 0; d < NO; ++d) {
            float x = o[mi][d] * inv;
            if constexpr (SILU) x = x / (1.0f + __expf(-x));
            vals[d] = x;
        }
        float* orow = ob + (size_t)i * ldo;
        *(float4*)&orow[tx * 4] = make_float4(vals[0], vals[1], vals[2], vals[3]);
        if constexpr (DV == 128)
            *(float4*)&orow[64 + tx * 4] = make_float4(vals[4], vals[5], vals[6], vals[7]);
    }
}

// ---------------------------------------------------------------------------
extern "C" void kernel_launch(void* const* d_in, const int* in_sizes, int n_in,
                              void* d_out, int out_size, void* d_ws, size_t ws_size,
                              hipStream_t stream)
{
    (void)in_sizes; (void)n_in; (void)out_size; (void)ws_size;
    const float* queries = (const float*)d_in[0];  // [2,2048,1024]
    const float* kvin    = (const float*)d_in[1];  // [2,2048,1024]
    const float* Wq      = (const float*)d_in[2];  // [1024,1024]
    const float* Wk1     = (const float*)d_in[3];  // [1024,1024]
    const float* Wv1     = (const float*)d_in[4];  // [1024,2048]
    const float* Wk2     = (const float*)d_in[5];  // [1024,2048]
    const float* Wv2     = (const float*)d_in[6];  // [1024,1024]
    const float* Wout    = (const float*)d_in[7];  // [1024,1024]
    const float* sink    = (const float*)d_in[8];  // [16]
    float* out = (float*)d_out;                    // [2,2048,1024]

    const int M = NB * NSEQ;  // 4096
    float* ws  = (float*)d_ws;
    float* Cq  = ws;                        // [4096,1024]
    float* Ckv = ws + (size_t)M * 1024;     // [4096,6144] = k1|v1|k2|v2
    float* H2  = Ckv + (size_t)M * 6144;    // [4096,2048] silu(hiddens), merged
    float* AO  = Cq;                        // alias: Cq dead after attend1

    dim3 blk(256);

    // projections
    gemm_f32<<<dim3(8, 32),  blk, 0, stream>>>(queries, Wq,  Cq,         M, 1024, 1024, 1024, 1024);
    gemm_f32<<<dim3(8, 32),  blk, 0, stream>>>(kvin,    Wk1, Ckv + 0,    M, 1024, 1024, 1024, 6144);
    gemm_f32<<<dim3(16, 32), blk, 0, stream>>>(kvin,    Wv1, Ckv + 1024, M, 2048, 1024, 2048, 6144);
    gemm_f32<<<dim3(16, 32), blk, 0, stream>>>(kvin,    Wk2, Ckv + 3072, M, 2048, 1024, 2048, 6144);
    gemm_f32<<<dim3(8, 32),  blk, 0, stream>>>(kvin,    Wv2, Ckv + 5120, M, 1024, 1024, 1024, 6144);

    // attend 1: q[.,64] x k1[.,64] -> v1[.,128]; silu fused; out merged [4096,2048]
    attend<64, 128, true><<<dim3(NB * NH, NSEQ / 64), blk, 0, stream>>>(
        Cq, 1024, Ckv, 6144, Ckv + 1024, 6144, sink, H2, 2048);

    // attend 2: h[.,128] x k2[.,128] -> v2[.,64]; out merged [4096,1024]
    attend<128, 64, false><<<dim3(NB * NH, NSEQ / 32), blk, 0, stream>>>(
        H2, 2048, Ckv + 3072, 6144, Ckv + 5120, 6144, sink, AO, 1024);

    // final projection
    gemm_f32<<<dim3(8, 32), blk, 0, stream>>>(AO, Wout, out, M, 1024, 1024, 1024, 1024);
}

// Round 2
// 490.486 us; speedup vs baseline: 5.5157x; 5.5157x over previous
//
#include <hip/hip_runtime.h>
#include <cstddef>
#include <cstdint>

#define NSEQ 2048
#define NB 2
#define NH 16
#define WINDOW 512

typedef __attribute__((ext_vector_type(8))) short short8;          // bf16x8 MFMA operand (4 VGPRs)
typedef __attribute__((ext_vector_type(4))) float f32x4;           // MFMA accumulator
typedef __attribute__((ext_vector_type(4))) unsigned short ushort4v;

// f32 -> bf16 RNE (bit trick; values are finite here)
__device__ __forceinline__ unsigned short f2bf(float f) {
    union { float f; unsigned u; } v; v.f = f;
    unsigned r = v.u + 0x7FFFu + ((v.u >> 16) & 1u);
    return (unsigned short)(r >> 16);
}

// async global->LDS, 16B per lane. HW semantics: dest = wave-uniform base + lane*16,
// so every call site keeps lane-consecutive dests; global src is per-lane (pre-swizzle there).
typedef const __attribute__((address_space(1))) unsigned int* gasp;
typedef __attribute__((address_space(3))) unsigned int* lasp;
__device__ __forceinline__ void gll16(const void* g, void* l) {
    __builtin_amdgcn_global_load_lds((gasp)g, (lasp)l, 16, 0, 0);
}

__device__ __forceinline__ f32x4 mfma16(short8 a, short8 b, f32x4 c) {
    return __builtin_amdgcn_mfma_f32_16x16x32_bf16(a, b, c, 0, 0, 0);
}

// ---------------------------------------------------------------------------
// elementwise f32 -> bf16 cast (4 elems/thread)
// ---------------------------------------------------------------------------
__global__ __launch_bounds__(256)
void castk(const float* __restrict__ in, unsigned short* __restrict__ out, int n4) {
    int i = blockIdx.x * 256 + threadIdx.x;
    if (i < n4) {
        float4 v = ((const float4*)in)[i];
        ushort4v o;
        o[0] = f2bf(v.x); o[1] = f2bf(v.y); o[2] = f2bf(v.z); o[3] = f2bf(v.w);
        ((ushort4v*)out)[i] = o;
    }
}

// ---------------------------------------------------------------------------
// W[K][N] f32 -> Wt[N][K] bf16 (GEMM wants B^T so B-fragments are k-contiguous)
// ---------------------------------------------------------------------------
__global__ __launch_bounds__(256)
void wtrans(const float* __restrict__ Wsrc, unsigned short* __restrict__ Wt, int K, int N) {
    __shared__ float tile[32][33];
    const int tx = threadIdx.x, ty = threadIdx.y;     // (32, 8)
    const int n0 = blockIdx.x * 32, k0 = blockIdx.y * 32;
#pragma unroll
    for (int i = 0; i < 4; ++i)
        tile[ty + i * 8][tx] = Wsrc[(size_t)(k0 + ty + i * 8) * N + n0 + tx];
    __syncthreads();
#pragma unroll
    for (int i = 0; i < 4; ++i)
        Wt[(size_t)(n0 + ty + i * 8) * K + k0 + tx] = f2bf(tile[tx][ty + i * 8]);
}

// ---------------------------------------------------------------------------
// bf16 MFMA GEMM, m97 structure: 128x128 tile, BK=32, 4 waves (each 64x64),
// global_load_lds(16B) staging, ds_read_b128 fragments, 16 MFMA/K-step/wave.
// A [M][K] bf16 row-major, Bt [N][K] bf16 (= B^T). Output modes:
//   OUT_F32: f32 [M][ldc]   OUT_BF16: bf16 [M][ldc]
//   OUT_VT : bf16 per-head transposed Vt[(b*NH+h)*DVH + d][NSEQ]  (h=col/DVH,d=col%DVH)
// ---------------------------------------------------------------------------
#define OUT_F32 0
#define OUT_BF16 1
#define OUT_VT 2

template <int OMODE, int DVH>
__global__ __launch_bounds__(256)
void gemm_bf16(const unsigned short* __restrict__ A,
               const unsigned short* __restrict__ Bt,
               void* __restrict__ Cout, int K, int ldc)
{
    __shared__ __align__(16) unsigned short As[128 * 32];
    __shared__ __align__(16) unsigned short Bs[128 * 32];
    const int t = threadIdx.x;
    const int l = t & 63, w = t >> 6;
    const int q = l & 15, g = l >> 4;
    const int bm = blockIdx.y * 128, bn = blockIdx.x * 128;
    const int wm = (w & 1) * 64, wn = (w >> 1) * 64;

    f32x4 acc[4][4];
    const f32x4 zero = {0.f, 0.f, 0.f, 0.f};
#pragma unroll
    for (int i = 0; i < 4; ++i)
#pragma unroll
        for (int j = 0; j < 4; ++j) acc[i][j] = zero;

    const unsigned short* Abase = A + (size_t)bm * K;
    const unsigned short* Bbase = Bt + (size_t)bn * K;

    for (int k0 = 0; k0 < K; k0 += 32) {
        __syncthreads();                       // prev MFMAs done reading LDS
#pragma unroll
        for (int it = 0; it < 2; ++it) {       // 512 chunks each of A,B; c->row c>>2, seg c&3
            int c = w * 128 + it * 64 + l;
            int r = c >> 2, sg = c & 3;
            gll16(Abase + (size_t)r * K + k0 + sg * 8, (char*)As + c * 16);
            gll16(Bbase + (size_t)r * K + k0 + sg * 8, (char*)Bs + c * 16);
        }
        __syncthreads();                       // vmcnt drained -> tile ready
        short8 a[4], b[4];
#pragma unroll
        for (int ms = 0; ms < 4; ++ms)
            a[ms] = *(const short8*)(As + (wm + ms * 16 + q) * 32 + g * 8);
#pragma unroll
        for (int ns = 0; ns < 4; ++ns)
            b[ns] = *(const short8*)(Bs + (wn + ns * 16 + q) * 32 + g * 8);
#pragma unroll
        for (int ms = 0; ms < 4; ++ms)
#pragma unroll
            for (int ns = 0; ns < 4; ++ns)
                acc[ms][ns] = mfma16(a[ms], b[ns], acc[ms][ns]);
    }

    // C/D layout (m89-verified): col = lane&15, row = (lane>>4)*4 + reg
    if constexpr (OMODE == OUT_F32) {
        float* C = (float*)Cout;
#pragma unroll
        for (int ms = 0; ms < 4; ++ms)
#pragma unroll
            for (int r = 0; r < 4; ++r) {
                int row = bm + wm + ms * 16 + g * 4 + r;
                float* crow = C + (size_t)row * ldc + bn + wn;
#pragma unroll
                for (int ns = 0; ns < 4; ++ns) crow[ns * 16 + q] = acc[ms][ns][r];
            }
    } else if constexpr (OMODE == OUT_BF16) {
        unsigned short* C = (unsigned short*)Cout;
#pragma unroll
        for (int ms = 0; ms < 4; ++ms)
#pragma unroll
            for (int r = 0; r < 4; ++r) {
                int row = bm + wm + ms * 16 + g * 4 + r;
                unsigned short* crow = C + (size_t)row * ldc + bn + wn;
#pragma unroll
                for (int ns = 0; ns < 4; ++ns) crow[ns * 16 + q] = f2bf(acc[ms][ns][r]);
            }
    } else {
        unsigned short* C = (unsigned short*)Cout;
#pragma unroll
        for (int ms = 0; ms < 4; ++ms) {
            int row0 = bm + wm + ms * 16 + g * 4;   // 4 consecutive tokens (same batch: 4|2048)
            int bb = row0 >> 11, nn = row0 & 2047;
#pragma unroll
            for (int ns = 0; ns < 4; ++ns) {
                int col = bn + wn + ns * 16 + q;
                int h = col / DVH, d = col % DVH;
                ushort4v pk;
#pragma unroll
                for (int r = 0; r < 4; ++r) pk[r] = f2bf(acc[ms][ns][r]);
                *(ushort4v*)(C + ((size_t)((bb * NH + h) * DVH + d)) * NSEQ + nn) = pk;
            }
        }
    }
}

// ---------------------------------------------------------------------------
// MFMA flash attend with sink + band mask (mask j>i && j-i<=WINDOW).
// 4 waves x 16 q-rows = 64 q / block; KT=64 kv per tile.
// Swapped QK^T: St = K·Q^T (A=K rows kv=l&15 k-contig; B=Q^T cols q=l&15) so each
// lane's softmax row q is fixed (=l&15) and kv spreads over regs+lane-groups.
// P -> bf16 -> XOR-swizzled LDS -> PV A-operand (b128). V pre-transposed in global
// ([.][d][n]) so Vt LDS tile is linear for global_load_lds; all LDS tiles use the
// seg^=(row&7) swizzle (G4/T2) with pre-swizzled global sources.
// ---------------------------------------------------------------------------
template <int DK, int DV, bool SILU, bool Q_PH, bool O_PH>
__global__ __launch_bounds__(256)
void attend_mfma(const unsigned short* __restrict__ Qg,
                 const unsigned short* __restrict__ Kg,
                 const unsigned short* __restrict__ Vtg,
                 const float* __restrict__ sink,
                 unsigned short* __restrict__ Og)
{
    constexpr int KT = 64;
    constexpr int NS = DV / 16;       // PV n-subtiles
    constexpr int NDB = DK / 32;      // QK k-blocks
    constexpr int KROWB = DK * 2;     // K LDS row bytes
    constexpr int KSEGS = KROWB / 16;

    __shared__ __align__(16) char KsB[64 * DK * 2];
    __shared__ __align__(16) char VtB[DV * 64 * 2];
    __shared__ __align__(16) char PsB[64 * 128];

    const int t = threadIdx.x, l = t & 63, w = t >> 6;
    const int q = l & 15, g = l >> 4;
    const int bh = blockIdx.x, bi = bh >> 4, h = bh & 15;
    const int i0 = blockIdx.y * 64;
    const int iq = i0 + w * 16 + q;       // this lane's softmax q-row
    const int qrow = w * 16 + q;          // Ps row

    const unsigned short* qbase;
    if constexpr (Q_PH)
        qbase = Qg + ((size_t)((bi * NH + h) * NSEQ + iq)) * DK;
    else
        qbase = Qg + ((size_t)(bi * NSEQ + iq)) * (NH * DK) + h * DK;
    short8 qf[NDB];
#pragma unroll
    for (int db = 0; db < NDB; ++db)
        qf[db] = *(const short8*)(qbase + db * 32 + g * 8);

    float m = sink[h], lsum = 1.0f;
    f32x4 o[NS];
    const f32x4 zero = {0.f, 0.f, 0.f, 0.f};
#pragma unroll
    for (int ns = 0; ns < NS; ++ns) o[ns] = zero;

    const unsigned short* kbase = Kg + (size_t)(bi * NSEQ) * (NH * DK) + h * DK;
    const unsigned short* vbase = Vtg + (size_t)((bi * NH + h) * DV) * NSEQ;

    for (int j0 = 0; j0 < NSEQ; j0 += KT) {
        const int dd = j0 - i0;
        if (dd >= KT && dd <= WINDOW - KT) continue;   // tile fully masked

        __syncthreads();    // everyone done with previous K/V tile
        // stage K tile [64][DK], swizzled: stored seg = src seg ^ (kv&7)
#pragma unroll
        for (int it = 0; it < (64 * KSEGS) / 256; ++it) {
            int c = w * (64 * KSEGS / 4) + it * 64 + l;
            int kv = c / KSEGS, sgst = c % KSEGS;
            int sgsrc = sgst ^ (kv & 7);
            gll16(kbase + (size_t)(j0 + kv) * (NH * DK) + sgsrc * 8, KsB + c * 16);
        }
        // stage Vt tile [DV][64], swizzled by d&7
#pragma unroll
        for (int it = 0; it < (DV * 8) / 256; ++it) {
            int c = w * (DV * 8 / 4) + it * 64 + l;
            int d = c >> 3, sgst = c & 7;
            int sgsrc = sgst ^ (d & 7);
            gll16(vbase + (size_t)d * NSEQ + j0 + sgsrc * 8, VtB + c * 16);
        }
        __syncthreads();    // tiles ready (vmcnt drained at barrier)

        // St = K·Q^T : st[s][r] = S[kv = j0+s*16+g*4+r][q-col = l&15]
        float st[4][4];
#pragma unroll
        for (int s = 0; s < 4; ++s) {
            f32x4 sacc = zero;
            int kvr = s * 16 + q;
#pragma unroll
            for (int db = 0; db < NDB; ++db) {
                short8 kf = *(const short8*)(KsB + kvr * KROWB + (((db * 4 + g) ^ (kvr & 7)) << 4));
                sacc = mfma16(kf, qf[db], sacc);
            }
#pragma unroll
            for (int r = 0; r < 4; ++r) st[s][r] = sacc[r];
        }

        // scale, mask, online softmax (row = fixed q per lane; reduce across groups)
        float mx = -3.0e38f;
#pragma unroll
        for (int s = 0; s < 4; ++s)
#pragma unroll
            for (int r = 0; r < 4; ++r) {
                int j = j0 + s * 16 + g * 4 + r;
                float v = st[s][r] * 0.125f;
                if (j > iq && (j - iq) <= WINDOW) v = -3.0e38f;
                st[s][r] = v;
                mx = fmaxf(mx, v);
            }
        mx = fmaxf(mx, __shfl_xor(mx, 16));
        mx = fmaxf(mx, __shfl_xor(mx, 32));
        const float nm = fmaxf(m, mx);
        const float corr = __expf(m - nm);
        m = nm;
        float ps = 0.f;
#pragma unroll
        for (int s = 0; s < 4; ++s) {
            ushort4v pk;
#pragma unroll
            for (int r = 0; r < 4; ++r) {
                float p = __expf(st[s][r] - nm);
                ps += p;
                pk[r] = f2bf(p);
            }
            *(ushort4v*)(PsB + qrow * 128 + ((s * 32 + g * 8) ^ ((q & 7) << 4))) = pk;
        }
        ps += __shfl_xor(ps, 16);
        ps += __shfl_xor(ps, 32);
        lsum = lsum * corr + ps;

        // rescale o: o-frag rows are q' = g*4+r -> fetch corr from lane q'
        float cr[4];
#pragma unroll
        for (int r = 0; r < 4; ++r) cr[r] = __shfl(corr, g * 4 + r);
#pragma unroll
        for (int ns = 0; ns < NS; ++ns)
#pragma unroll
            for (int r = 0; r < 4; ++r) o[ns][r] *= cr[r];

        // PV: A = P (rows q = l&15, kv contiguous), B = V (cols d = l&15, kv contiguous)
#pragma unroll
        for (int kb = 0; kb < 2; ++kb) {
            short8 pf = *(const short8*)(PsB + qrow * 128 + ((((kb * 4 + g) ^ (q & 7))) << 4));
#pragma unroll
            for (int ns = 0; ns < NS; ++ns) {
                int d = ns * 16 + q;
                short8 vf = *(const short8*)(VtB + d * 128 + (((kb * 4 + g) ^ (d & 7)) << 4));
                o[ns] = mfma16(pf, vf, o[ns]);
            }
        }
    }

    // epilogue: normalize (+silu), write bf16. o-frag: row q' = g*4+r, col d = ns*16 + l&15
    const float inv = 1.0f / lsum;
    float ivr[4];
#pragma unroll
    for (int r = 0; r < 4; ++r) ivr[r] = __shfl(inv, g * 4 + r);
#pragma unroll
    for (int ns = 0; ns < NS; ++ns)
#pragma unroll
        for (int r = 0; r < 4; ++r) {
            float x = o[ns][r] * ivr[r];
            if constexpr (SILU) x = x / (1.0f + __expf(-x));
            int qr = i0 + w * 16 + g * 4 + r;
            int d = ns * 16 + q;
            size_t off;
            if constexpr (O_PH)
                off = ((size_t)((bi * NH + h) * NSEQ + qr)) * DV + d;
            else
                off = ((size_t)(bi * NSEQ + qr)) * (NH * DV) + h * DV + d;
            Og[off] = f2bf(x);
        }
}

// ---------------------------------------------------------------------------
extern "C" void kernel_launch(void* const* d_in, const int* in_sizes, int n_in,
                              void* d_out, int out_size, void* d_ws, size_t ws_size,
                              hipStream_t stream)
{
    (void)in_sizes; (void)n_in; (void)out_size; (void)ws_size;
    const float* queries = (const float*)d_in[0];
    const float* kvin    = (const float*)d_in[1];
    const float* Wq      = (const float*)d_in[2];
    const float* Wk1     = (const float*)d_in[3];
    const float* Wv1     = (const float*)d_in[4];
    const float* Wk2     = (const float*)d_in[5];
    const float* Wv2     = (const float*)d_in[6];
    const float* Wout    = (const float*)d_in[7];
    const float* sink    = (const float*)d_in[8];
    float* out = (float*)d_out;

    unsigned short* Xq   = (unsigned short*)d_ws;                   // [4096][1024]
    unsigned short* Xkv  = Xq   + (size_t)4096 * 1024;              // [4096][1024]
    unsigned short* Wqt  = Xkv  + (size_t)4096 * 1024;              // [1024][1024]
    unsigned short* Wk1t = Wqt  + (size_t)1024 * 1024;
    unsigned short* Wv1t = Wk1t + (size_t)1024 * 1024;              // [2048][1024]
    unsigned short* Wk2t = Wv1t + (size_t)2048 * 1024;              // [2048][1024]
    unsigned short* Wv2t = Wk2t + (size_t)2048 * 1024;              // [1024][1024]
    unsigned short* Wot  = Wv2t + (size_t)1024 * 1024;              // [1024][1024]
    unsigned short* Qp   = Wot  + (size_t)1024 * 1024;              // [4096][1024]
    unsigned short* K1p  = Qp   + (size_t)4096 * 1024;              // [4096][1024]
    unsigned short* V1t  = K1p  + (size_t)4096 * 1024;              // [2*16*128][2048]
    unsigned short* K2p  = V1t  + (size_t)2 * 16 * 128 * 2048;      // [4096][2048]
    unsigned short* V2t  = K2p  + (size_t)4096 * 2048;              // [2*16*64][2048]
    unsigned short* Hb   = V2t  + (size_t)2 * 16 * 64 * 2048;       // [2*16*2048][128]
    unsigned short* AO   = Hb   + (size_t)2 * 16 * 2048 * 128;      // [4096][1024]

    dim3 blk(256);
    dim3 tblk(32, 8);

    castk<<<4096, blk, 0, stream>>>(queries, Xq, 1048576);
    castk<<<4096, blk, 0, stream>>>(kvin, Xkv, 1048576);
    wtrans<<<dim3(32, 32), tblk, 0, stream>>>(Wq,   Wqt,  1024, 1024);
    wtrans<<<dim3(32, 32), tblk, 0, stream>>>(Wk1,  Wk1t, 1024, 1024);
    wtrans<<<dim3(64, 32), tblk, 0, stream>>>(Wv1,  Wv1t, 1024, 2048);
    wtrans<<<dim3(64, 32), tblk, 0, stream>>>(Wk2,  Wk2t, 1024, 2048);
    wtrans<<<dim3(32, 32), tblk, 0, stream>>>(Wv2,  Wv2t, 1024, 1024);
    wtrans<<<dim3(32, 32), tblk, 0, stream>>>(Wout, Wot,  1024, 1024);

    gemm_bf16<OUT_BF16, 1><<<dim3(8, 32), blk, 0, stream>>>(Xq,  Wqt,  Qp,  1024, 1024);
    gemm_bf16<OUT_BF16, 1><<<dim3(8, 32), blk, 0, stream>>>(Xkv, Wk1t, K1p, 1024, 1024);
    gemm_bf16<OUT_VT, 128><<<dim3(16, 32), blk, 0, stream>>>(Xkv, Wv1t, V1t, 1024, 0);
    gemm_bf16<OUT_BF16, 1><<<dim3(16, 32), blk, 0, stream>>>(Xkv, Wk2t, K2p, 1024, 2048);
    gemm_bf16<OUT_VT, 64><<<dim3(8, 32), blk, 0, stream>>>(Xkv, Wv2t, V2t, 1024, 0);

    // attend1: Q=Qp (merged), K=K1p, V=V1t -> H per-head [b,h,n,128], silu fused
    attend_mfma<64, 128, true, false, true><<<dim3(32, 32), blk, 0, stream>>>(
        Qp, K1p, V1t, sink, Hb);
    // attend2: Q=H (per-head), K=K2p, V=V2t -> AO merged [4096][1024]
    attend_mfma<128, 64, false, true, false><<<dim3(32, 32), blk, 0, stream>>>(
        Hb, K2p, V2t, sink, AO);

    gemm_bf16<OUT_F32, 1><<<dim3(8, 32), blk, 0, stream>>>(AO, Wot, out, 1024, 1024);
}

// Round 3
// 426.157 us; speedup vs baseline: 6.3483x; 1.1510x over previous
//
#include <hip/hip_runtime.h>
#include <cstddef>
#include <cstdint>

#define NSEQ 2048
#define NB 2
#define NH 16
#define WINDOW 512

#define LOG2E 1.44269504088896f
#define QSCALE 0.180336877396f   // 0.125 * log2(e): folded into Q so softmax is base-2

typedef __attribute__((ext_vector_type(8))) short short8;          // bf16x8 MFMA operand
typedef __attribute__((ext_vector_type(4))) float f32x4;           // MFMA accumulator
typedef __attribute__((ext_vector_type(4))) unsigned short ushort4v;

// f32 -> bf16 RNE (bit trick; values are finite here)
__device__ __forceinline__ unsigned short f2bf(float f) {
    union { float f; unsigned u; } v; v.f = f;
    unsigned r = v.u + 0x7FFFu + ((v.u >> 16) & 1u);
    return (unsigned short)(r >> 16);
}

// pack 2 f32 -> 2 bf16 in one u32 (lo=a, hi=b)
__device__ __forceinline__ unsigned cvt_pk_bf16(float a, float b) {
    unsigned r;
    asm("v_cvt_pk_bf16_f32 %0, %1, %2" : "=v"(r) : "v"(a), "v"(b));
    return r;
}

// async global->LDS, 16B per lane (dest = wave-uniform base + lane*16)
typedef const __attribute__((address_space(1))) unsigned int* gasp;
typedef __attribute__((address_space(3))) unsigned int* lasp;
__device__ __forceinline__ void gll16(const void* g, void* l) {
    __builtin_amdgcn_global_load_lds((gasp)g, (lasp)l, 16, 0, 0);
}

__device__ __forceinline__ f32x4 mfma16(short8 a, short8 b, f32x4 c) {
    return __builtin_amdgcn_mfma_f32_16x16x32_bf16(a, b, c, 0, 0, 0);
}

// ---------------------------------------------------------------------------
// elementwise f32 -> bf16 cast (4 elems/thread)
// ---------------------------------------------------------------------------
__global__ __launch_bounds__(256)
void castk(const float* __restrict__ in, unsigned short* __restrict__ out, int n4) {
    int i = blockIdx.x * 256 + threadIdx.x;
    if (i < n4) {
        float4 v = ((const float4*)in)[i];
        ushort4v o;
        o[0] = f2bf(v.x); o[1] = f2bf(v.y); o[2] = f2bf(v.z); o[3] = f2bf(v.w);
        ((ushort4v*)out)[i] = o;
    }
}

// ---------------------------------------------------------------------------
// W[K][N] f32 -> Wt[N][K] bf16
// ---------------------------------------------------------------------------
__global__ __launch_bounds__(256)
void wtrans(const float* __restrict__ Wsrc, unsigned short* __restrict__ Wt, int K, int N) {
    __shared__ float tile[32][33];
    const int tx = threadIdx.x, ty = threadIdx.y;     // (32, 8)
    const int n0 = blockIdx.x * 32, k0 = blockIdx.y * 32;
#pragma unroll
    for (int i = 0; i < 4; ++i)
        tile[ty + i * 8][tx] = Wsrc[(size_t)(k0 + ty + i * 8) * N + n0 + tx];
    __syncthreads();
#pragma unroll
    for (int i = 0; i < 4; ++i)
        Wt[(size_t)(n0 + ty + i * 8) * K + k0 + tx] = f2bf(tile[tx][ty + i * 8]);
}

// ---------------------------------------------------------------------------
// bf16 MFMA GEMM, m97 structure: 128x128 tile, BK=32, 4 waves (each 64x64).
// A [M][K] bf16 row-major, Bt [N][K] bf16 (= B^T). Output modes:
//   OUT_F32 : f32 [M][ldc]
//   OUT_BF16: bf16 [M][ldc], scaled by oscale
//   OUT_KV  : merged k1|v1|k2|v2 projection (N=6144) routed to 4 buffers;
//             V outputs stored per-head transposed [(b*NH+h)*DVH+d][NSEQ]
// ---------------------------------------------------------------------------
#define OUT_F32 0
#define OUT_BF16 1
#define OUT_KV 2

template <int OMODE>
__global__ __launch_bounds__(256)
void gemm_bf16(const unsigned short* __restrict__ A,
               const unsigned short* __restrict__ Bt,
               void* __restrict__ Cout, int K, int ldc, float oscale,
               unsigned short* __restrict__ K1p, unsigned short* __restrict__ V1t,
               unsigned short* __restrict__ K2p, unsigned short* __restrict__ V2t)
{
    __shared__ __align__(16) unsigned short As[128 * 32];
    __shared__ __align__(16) unsigned short Bs[128 * 32];
    const int t = threadIdx.x;
    const int l = t & 63, w = t >> 6;
    const int q = l & 15, g = l >> 4;
    const int bm = blockIdx.y * 128, bn = blockIdx.x * 128;
    const int wm = (w & 1) * 64, wn = (w >> 1) * 64;

    f32x4 acc[4][4];
    const f32x4 zero = {0.f, 0.f, 0.f, 0.f};
#pragma unroll
    for (int i = 0; i < 4; ++i)
#pragma unroll
        for (int j = 0; j < 4; ++j) acc[i][j] = zero;

    const unsigned short* Abase = A + (size_t)bm * K;
    const unsigned short* Bbase = Bt + (size_t)bn * K;

    for (int k0 = 0; k0 < K; k0 += 32) {
        __syncthreads();
#pragma unroll
        for (int it = 0; it < 2; ++it) {
            int c = w * 128 + it * 64 + l;
            int r = c >> 2, sg = c & 3;
            gll16(Abase + (size_t)r * K + k0 + sg * 8, (char*)As + c * 16);
            gll16(Bbase + (size_t)r * K + k0 + sg * 8, (char*)Bs + c * 16);
        }
        __syncthreads();
        short8 a[4], b[4];
#pragma unroll
        for (int ms = 0; ms < 4; ++ms)
            a[ms] = *(const short8*)(As + (wm + ms * 16 + q) * 32 + g * 8);
#pragma unroll
        for (int ns = 0; ns < 4; ++ns)
            b[ns] = *(const short8*)(Bs + (wn + ns * 16 + q) * 32 + g * 8);
#pragma unroll
        for (int ms = 0; ms < 4; ++ms)
#pragma unroll
            for (int ns = 0; ns < 4; ++ns)
                acc[ms][ns] = mfma16(a[ms], b[ns], acc[ms][ns]);
    }

    // C/D layout: col = lane&15, row = (lane>>4)*4 + reg
    if constexpr (OMODE == OUT_F32) {
        float* C = (float*)Cout;
#pragma unroll
        for (int ms = 0; ms < 4; ++ms)
#pragma unroll
            for (int r = 0; r < 4; ++r) {
                int row = bm + wm + ms * 16 + g * 4 + r;
                float* crow = C + (size_t)row * ldc + bn + wn;
#pragma unroll
                for (int ns = 0; ns < 4; ++ns) crow[ns * 16 + q] = acc[ms][ns][r] * oscale;
            }
    } else if constexpr (OMODE == OUT_BF16) {
        unsigned short* C = (unsigned short*)Cout;
#pragma unroll
        for (int ms = 0; ms < 4; ++ms)
#pragma unroll
            for (int r = 0; r < 4; ++r) {
                int row = bm + wm + ms * 16 + g * 4 + r;
                unsigned short* crow = C + (size_t)row * ldc + bn + wn;
#pragma unroll
                for (int ns = 0; ns < 4; ++ns) crow[ns * 16 + q] = f2bf(acc[ms][ns][r] * oscale);
            }
    } else {
        const int colbase = bn + wn;   // 64-aligned; each 1024-range is uniform per half-wave-tile
        if (colbase < 1024) {          // K1 merged [4096][1024]
#pragma unroll
            for (int ms = 0; ms < 4; ++ms)
#pragma unroll
                for (int r = 0; r < 4; ++r) {
                    int row = bm + wm + ms * 16 + g * 4 + r;
                    unsigned short* crow = K1p + (size_t)row * 1024 + colbase;
#pragma unroll
                    for (int ns = 0; ns < 4; ++ns) crow[ns * 16 + q] = f2bf(acc[ms][ns][r]);
                }
        } else if (colbase < 3072) {   // V1 per-head transposed, DVH=128
#pragma unroll
            for (int ms = 0; ms < 4; ++ms) {
                int row0 = bm + wm + ms * 16 + g * 4;
                int bb = row0 >> 11, nn = row0 & 2047;
#pragma unroll
                for (int ns = 0; ns < 4; ++ns) {
                    int c2 = colbase - 1024 + ns * 16 + q;
                    int h = c2 >> 7, d = c2 & 127;
                    ushort4v pk;
#pragma unroll
                    for (int r = 0; r < 4; ++r) pk[r] = f2bf(acc[ms][ns][r]);
                    *(ushort4v*)(V1t + ((size_t)((bb * NH + h) * 128 + d)) * NSEQ + nn) = pk;
                }
            }
        } else if (colbase < 5120) {   // K2 merged [4096][2048]
#pragma unroll
            for (int ms = 0; ms < 4; ++ms)
#pragma unroll
                for (int r = 0; r < 4; ++r) {
                    int row = bm + wm + ms * 16 + g * 4 + r;
                    unsigned short* crow = K2p + (size_t)row * 2048 + colbase - 3072;
#pragma unroll
                    for (int ns = 0; ns < 4; ++ns) crow[ns * 16 + q] = f2bf(acc[ms][ns][r]);
                }
        } else {                       // V2 per-head transposed, DVH=64
#pragma unroll
            for (int ms = 0; ms < 4; ++ms) {
                int row0 = bm + wm + ms * 16 + g * 4;
                int bb = row0 >> 11, nn = row0 & 2047;
#pragma unroll
                for (int ns = 0; ns < 4; ++ns) {
                    int c2 = colbase - 5120 + ns * 16 + q;
                    int h = c2 >> 6, d = c2 & 63;
                    ushort4v pk;
#pragma unroll
                    for (int r = 0; r < 4; ++r) pk[r] = f2bf(acc[ms][ns][r]);
                    *(ushort4v*)(V2t + ((size_t)((bb * NH + h) * 64 + d)) * NSEQ + nn) = pk;
                }
            }
        }
    }
}

// ---------------------------------------------------------------------------
// MFMA flash attend. Q pre-scaled by 0.125*log2e upstream -> base-2 softmax.
// Sink folded as m0 = sink*log2e, l0 = 1. Band mask only on dd==0 / dd==WINDOW
// tiles (wave-uniform). T13 defer-rescale with THR=8 (log2 units).
// ---------------------------------------------------------------------------
template <int DK, int DV, bool SILU, bool Q_PH, bool O_PH>
__global__ __launch_bounds__(256)
void attend_mfma(const unsigned short* __restrict__ Qg,
                 const unsigned short* __restrict__ Kg,
                 const unsigned short* __restrict__ Vtg,
                 const float* __restrict__ sink,
                 unsigned short* __restrict__ Og)
{
    constexpr int KT = 64;
    constexpr int NS = DV / 16;
    constexpr int NDB = DK / 32;
    constexpr int KROWB = DK * 2;
    constexpr int KSEGS = KROWB / 16;

    __shared__ __align__(16) char KsB[64 * DK * 2];
    __shared__ __align__(16) char VtB[DV * 64 * 2];
    __shared__ __align__(16) char PsB[64 * 128];

    const int t = threadIdx.x, l = t & 63, w = t >> 6;
    const int q = l & 15, g = l >> 4;
    const int bh = blockIdx.x, bi = bh >> 4, h = bh & 15;
    const int i0 = blockIdx.y * 64;
    const int iq = i0 + w * 16 + q;
    const int qrow = w * 16 + q;

    const unsigned short* qbase;
    if constexpr (Q_PH)
        qbase = Qg + ((size_t)((bi * NH + h) * NSEQ + iq)) * DK;
    else
        qbase = Qg + ((size_t)(bi * NSEQ + iq)) * (NH * DK) + h * DK;
    short8 qf[NDB];
#pragma unroll
    for (int db = 0; db < NDB; ++db)
        qf[db] = *(const short8*)(qbase + db * 32 + g * 8);

    float m = sink[h] * LOG2E, lsum = 1.0f;
    f32x4 o[NS];
    const f32x4 zero = {0.f, 0.f, 0.f, 0.f};
#pragma unroll
    for (int ns = 0; ns < NS; ++ns) o[ns] = zero;

    const unsigned short* kbase = Kg + (size_t)(bi * NSEQ) * (NH * DK) + h * DK;
    const unsigned short* vbase = Vtg + (size_t)((bi * NH + h) * DV) * NSEQ;

    for (int j0 = 0; j0 < NSEQ; j0 += KT) {
        const int dd = j0 - i0;
        if (dd >= KT && dd <= WINDOW - KT) continue;   // tile fully masked

        __syncthreads();
        // stage K tile [64][DK] (seg-swizzled via pre-swizzled global src)
#pragma unroll
        for (int it = 0; it < (64 * KSEGS) / 256; ++it) {
            int c = w * (64 * KSEGS / 4) + it * 64 + l;
            int kv = c / KSEGS, sgst = c % KSEGS;
            int sgsrc = sgst ^ (kv & 7);
            gll16(kbase + (size_t)(j0 + kv) * (NH * DK) + sgsrc * 8, KsB + c * 16);
        }
        // stage Vt tile [DV][64]
#pragma unroll
        for (int it = 0; it < (DV * 8) / 256; ++it) {
            int c = w * (DV * 8 / 4) + it * 64 + l;
            int d = c >> 3, sgst = c & 7;
            int sgsrc = sgst ^ (d & 7);
            gll16(vbase + (size_t)d * NSEQ + j0 + sgsrc * 8, VtB + c * 16);
        }
        __syncthreads();

        // St = K·Q^T : st[s][r] = S[kv = s*16+g*4+r][q]
        float st[4][4];
#pragma unroll
        for (int s = 0; s < 4; ++s) {
            f32x4 sacc = zero;
            int kvr = s * 16 + q;
#pragma unroll
            for (int db = 0; db < NDB; ++db) {
                short8 kf = *(const short8*)(KsB + kvr * KROWB + (((db * 4 + g) ^ (kvr & 7)) << 4));
                sacc = mfma16(kf, qf[db], sacc);
            }
#pragma unroll
            for (int r = 0; r < 4; ++r) st[s][r] = sacc[r];
        }

        // band mask: only the diagonal and window-edge tiles have masked elems
        if (dd == 0 || dd == WINDOW) {
#pragma unroll
            for (int s = 0; s < 4; ++s)
#pragma unroll
                for (int r = 0; r < 4; ++r) {
                    int j = j0 + s * 16 + g * 4 + r;
                    if (j > iq && (j - iq) <= WINDOW) st[s][r] = -3.0e38f;
                }
        }

        float mx = st[0][0];
#pragma unroll
        for (int s = 0; s < 4; ++s)
#pragma unroll
            for (int r = 0; r < 4; ++r)
                if (s || r) mx = fmaxf(mx, st[s][r]);
        mx = fmaxf(mx, __shfl_xor(mx, 16));
        mx = fmaxf(mx, __shfl_xor(mx, 32));

        if (!__all(mx - m <= 8.0f)) {      // T13 defer-rescale
            const float nm = fmaxf(m, mx);
            const float corr = exp2f(m - nm);
            m = nm;
            lsum *= corr;
            float cr[4];
#pragma unroll
            for (int r = 0; r < 4; ++r) cr[r] = __shfl(corr, g * 4 + r);
#pragma unroll
            for (int ns = 0; ns < NS; ++ns)
#pragma unroll
                for (int r = 0; r < 4; ++r) o[ns][r] *= cr[r];
        }

        float ps = 0.f;
#pragma unroll
        for (int s = 0; s < 4; ++s) {
            float p0 = exp2f(st[s][0] - m);
            float p1 = exp2f(st[s][1] - m);
            float p2 = exp2f(st[s][2] - m);
            float p3 = exp2f(st[s][3] - m);
            ps += (p0 + p1) + (p2 + p3);
            uint2 pk;
            pk.x = cvt_pk_bf16(p0, p1);
            pk.y = cvt_pk_bf16(p2, p3);
            *(uint2*)(PsB + qrow * 128 + ((s * 32 + g * 8) ^ ((q & 7) << 4))) = pk;
        }
        ps += __shfl_xor(ps, 16);
        ps += __shfl_xor(ps, 32);
        lsum += ps;

        // PV
#pragma unroll
        for (int kb = 0; kb < 2; ++kb) {
            short8 pf = *(const short8*)(PsB + qrow * 128 + ((((kb * 4 + g) ^ (q & 7))) << 4));
#pragma unroll
            for (int ns = 0; ns < NS; ++ns) {
                int d = ns * 16 + q;
                short8 vf = *(const short8*)(VtB + d * 128 + (((kb * 4 + g) ^ (d & 7)) << 4));
                o[ns] = mfma16(pf, vf, o[ns]);
            }
        }
    }

    // epilogue
    const float inv = 1.0f / lsum;
    float ivr[4];
#pragma unroll
    for (int r = 0; r < 4; ++r) ivr[r] = __shfl(inv, g * 4 + r);
#pragma unroll
    for (int ns = 0; ns < NS; ++ns)
#pragma unroll
        for (int r = 0; r < 4; ++r) {
            float x = o[ns][r] * ivr[r];
            if constexpr (SILU) x = x / (1.0f + __expf(-x)) * QSCALE;  // silu, then next-stage q-scale
            int qr = i0 + w * 16 + g * 4 + r;
            int d = ns * 16 + q;
            size_t off;
            if constexpr (O_PH)
                off = ((size_t)((bi * NH + h) * NSEQ + qr)) * DV + d;
            else
                off = ((size_t)(bi * NSEQ + qr)) * (NH * DV) + h * DV + d;
            Og[off] = f2bf(x);
        }
}

// ---------------------------------------------------------------------------
extern "C" void kernel_launch(void* const* d_in, const int* in_sizes, int n_in,
                              void* d_out, int out_size, void* d_ws, size_t ws_size,
                              hipStream_t stream)
{
    (void)in_sizes; (void)n_in; (void)out_size; (void)ws_size;
    const float* queries = (const float*)d_in[0];
    const float* kvin    = (const float*)d_in[1];
    const float* Wq      = (const float*)d_in[2];
    const float* Wk1     = (const float*)d_in[3];
    const float* Wv1     = (const float*)d_in[4];
    const float* Wk2     = (const float*)d_in[5];
    const float* Wv2     = (const float*)d_in[6];
    const float* Wout    = (const float*)d_in[7];
    const float* sink    = (const float*)d_in[8];
    float* out = (float*)d_out;

    unsigned short* Xq   = (unsigned short*)d_ws;                   // [4096][1024]
    unsigned short* Xkv  = Xq   + (size_t)4096 * 1024;              // [4096][1024]
    unsigned short* Wqt  = Xkv  + (size_t)4096 * 1024;              // [1024][1024]
    unsigned short* Wk1t = Wqt  + (size_t)1024 * 1024;              // [6144][1024] merged from here
    unsigned short* Wv1t = Wk1t + (size_t)1024 * 1024;
    unsigned short* Wk2t = Wv1t + (size_t)2048 * 1024;
    unsigned short* Wv2t = Wk2t + (size_t)2048 * 1024;
    unsigned short* Wot  = Wv2t + (size_t)1024 * 1024;              // [1024][1024]
    unsigned short* Qp   = Wot  + (size_t)1024 * 1024;              // [4096][1024], pre-scaled
    unsigned short* K1p  = Qp   + (size_t)4096 * 1024;              // [4096][1024]
    unsigned short* V1t  = K1p  + (size_t)4096 * 1024;              // [2*16*128][2048]
    unsigned short* K2p  = V1t  + (size_t)2 * 16 * 128 * 2048;      // [4096][2048]
    unsigned short* V2t  = K2p  + (size_t)4096 * 2048;              // [2*16*64][2048]
    unsigned short* Hb   = V2t  + (size_t)2 * 16 * 64 * 2048;       // [2*16*2048][128], pre-scaled
    unsigned short* AO   = Hb   + (size_t)2 * 16 * 2048 * 128;      // [4096][1024]

    dim3 blk(256);
    dim3 tblk(32, 8);

    castk<<<4096, blk, 0, stream>>>(queries, Xq, 1048576);
    castk<<<4096, blk, 0, stream>>>(kvin, Xkv, 1048576);
    wtrans<<<dim3(32, 32), tblk, 0, stream>>>(Wq,   Wqt,  1024, 1024);
    wtrans<<<dim3(32, 32), tblk, 0, stream>>>(Wk1,  Wk1t, 1024, 1024);
    wtrans<<<dim3(64, 32), tblk, 0, stream>>>(Wv1,  Wv1t, 1024, 2048);
    wtrans<<<dim3(64, 32), tblk, 0, stream>>>(Wk2,  Wk2t, 1024, 2048);
    wtrans<<<dim3(32, 32), tblk, 0, stream>>>(Wv2,  Wv2t, 1024, 1024);
    wtrans<<<dim3(32, 32), tblk, 0, stream>>>(Wout, Wot,  1024, 1024);

    // Q projection (pre-scaled by 0.125*log2e for base-2 softmax)
    gemm_bf16<OUT_BF16><<<dim3(8, 32), blk, 0, stream>>>(
        Xq, Wqt, Qp, 1024, 1024, QSCALE, nullptr, nullptr, nullptr, nullptr);
    // merged K1|V1|K2|V2 projection: 4096 x 6144 x 1024, routed epilogue
    gemm_bf16<OUT_KV><<<dim3(48, 32), blk, 0, stream>>>(
        Xkv, Wk1t, nullptr, 1024, 0, 1.0f, K1p, V1t, K2p, V2t);

    attend_mfma<64, 128, true, false, true><<<dim3(32, 32), blk, 0, stream>>>(
        Qp, K1p, V1t, sink, Hb);
    attend_mfma<128, 64, false, true, false><<<dim3(32, 32), blk, 0, stream>>>(
        Hb, K2p, V2t, sink, AO);

    gemm_bf16<OUT_F32><<<dim3(8, 32), blk, 0, stream>>>(
        AO, Wot, out, 1024, 1024, 1.0f, nullptr, nullptr, nullptr, nullptr);
}